// Round 1
// baseline (46.232 us; speedup 1.0000x reference)
//
#include <hip/hip_runtime.h>

typedef __attribute__((ext_vector_type(4))) float f32x4;
typedef __attribute__((ext_vector_type(8))) __bf16 bf16x8;
typedef __attribute__((ext_vector_type(8))) unsigned short ushort8v;
typedef __attribute__((ext_vector_type(4))) unsigned short ushort4v;

#define NGRP  100
#define DDIM  768
#define FDIM  100
#define NCLS  10000
#define KS    64
#define NSTEP 12     // 768 / 64
#define MBLK  64
#define LDB   72     // B_lds row stride (64 k + 8 pad) in bf16 elems
#define NTILE 7      // 112 / 16 f-tiles

static __device__ __forceinline__ unsigned short f2bf(float f) {
    __bf16 b = (__bf16)f;                      // RNE convert (compiler pairs into v_cvt_pk_bf16_f32)
    return __builtin_bit_cast(unsigned short, b);
}

__global__ __launch_bounds__(256, 2) void gfcp_mfma(
    const float* __restrict__ H, const float* __restrict__ W,
    const float* __restrict__ Bv, float* __restrict__ Out)
{
    __shared__ unsigned short Blds[2][112 * LDB];   // 2 x 16128 B = 32.25 KB

    // XCD-bijective swizzle: 800 blocks, 8 XCDs -> 100 contiguous wgids per XCD.
    // Keeps all 8 row-blocks of a group on one XCD (W_i L2 reuse).
    const int bid  = blockIdx.x;
    const int wgid = (bid & 7) * 100 + (bid >> 3);
    const int g    = wgid >> 3;          // group 0..99
    const int m0   = (wgid & 7) * MBLK;  // row block 0..448

    const int tid  = threadIdx.x;
    const int lane = tid & 63;
    const int wv   = tid >> 6;           // wave 0..3
    const int r16  = lane & 15;          // M-row within tile / N-col within tile
    const int kg   = lane >> 4;          // 0..3, k-subgroup

    // B staging: 400 4x4 micro-tiles (16 kq x 25 fq) over 256 threads
    const int kq0 = tid / 25, fq0 = tid % 25;
    const bool has1 = (tid + 256) < 400;
    const int idx1 = tid + 256;
    const int kq1 = idx1 / 25, fq1 = idx1 % 25;

    const float* Wg   = W + (size_t)g * (DDIM * FDIM);
    const float* Arow = H + (size_t)(m0 + wv * 16 + r16) * (NGRP * DDIM)
                          + (size_t)g * DDIM + (size_t)kg * 8;

    f32x4 acc[NTILE];
#pragma unroll
    for (int t = 0; t < NTILE; ++t) acc[t] = (f32x4)(0.0f);

    f32x4 bA[2][4];   // two pipeline slots x 16 floats (A fragment source)
    f32x4 bB[8];      // B stage regs: 2 micro-tiles x 4 rows

    auto loadA = [&](int slot, int k0) {
        const float* p = Arow + k0;
        bA[slot][0] = *(const f32x4*)(p);
        bA[slot][1] = *(const f32x4*)(p + 4);
        bA[slot][2] = *(const f32x4*)(p + 32);
        bA[slot][3] = *(const f32x4*)(p + 36);
    };
    auto loadB = [&](int k0) {
        const float* p0 = Wg + (size_t)(k0 + kq0 * 4) * FDIM + fq0 * 4;
#pragma unroll
        for (int r = 0; r < 4; ++r) bB[r] = *(const f32x4*)(p0 + r * FDIM);
        if (has1) {
            const float* p1 = Wg + (size_t)(k0 + kq1 * 4) * FDIM + fq1 * 4;
#pragma unroll
            for (int r = 0; r < 4; ++r) bB[4 + r] = *(const f32x4*)(p1 + r * FDIM);
        }
    };
    auto writeB = [&](int buf) {   // in-register 4x4 transpose, ds_write_b64 per column
        unsigned short* bl = &Blds[buf][0];
#pragma unroll
        for (int c = 0; c < 4; ++c) {
            ushort4v v;
            v.x = f2bf(bB[0][c]); v.y = f2bf(bB[1][c]);
            v.z = f2bf(bB[2][c]); v.w = f2bf(bB[3][c]);
            *(ushort4v*)(bl + (fq0 * 4 + c) * LDB + kq0 * 4) = v;
        }
        if (has1) {
#pragma unroll
            for (int c = 0; c < 4; ++c) {
                ushort4v v;
                v.x = f2bf(bB[4][c]); v.y = f2bf(bB[5][c]);
                v.z = f2bf(bB[6][c]); v.w = f2bf(bB[7][c]);
                *(ushort4v*)(bl + (fq1 * 4 + c) * LDB + kq1 * 4) = v;
            }
        }
    };
    auto compute = [&](int buf, int slot) {
        const unsigned short* bl = &Blds[buf][0];
#pragma unroll
        for (int s = 0; s < 2; ++s) {
            const f32x4 a0 = bA[slot][s * 2 + 0];
            const f32x4 a1 = bA[slot][s * 2 + 1];
            ushort8v au;
            au[0] = f2bf(a0[0]); au[1] = f2bf(a0[1]); au[2] = f2bf(a0[2]); au[3] = f2bf(a0[3]);
            au[4] = f2bf(a1[0]); au[5] = f2bf(a1[1]); au[6] = f2bf(a1[2]); au[7] = f2bf(a1[3]);
            const bf16x8 af = __builtin_bit_cast(bf16x8, au);
            const int kb = s * 32 + kg * 8;
#pragma unroll
            for (int t = 0; t < NTILE; ++t) {
                const ushort8v bu = *(const ushort8v*)(bl + (t * 16 + r16) * LDB + kb);
                const bf16x8 bf = __builtin_bit_cast(bf16x8, bu);
                acc[t] = __builtin_amdgcn_mfma_f32_16x16x32_bf16(af, bf, acc[t], 0, 0, 0);
            }
        }
    };

    // ---- prologue ----
    loadB(0);
    loadA(0, 0);
    loadA(1, KS);
    writeB(0);          // waits on B(0) loads
    loadB(KS);          // B(1) in flight across step 0 compute
    __syncthreads();

    // ---- main loop: fully unrolled so all slot/buf indices are compile-time ----
#pragma unroll
    for (int t = 0; t < NSTEP; ++t) {
        const int cur = t & 1;
        compute(cur, cur);               // MFMA on buf[cur], A slot[cur]
        if (t + 1 < NSTEP) {
            writeB(cur ^ 1);             // B(t+1) regs -> other buffer
            if (t + 2 < NSTEP) {
                loadB((t + 2) * KS);     // issue next-next B
                loadA(cur, (t + 2) * KS);// issue next-next A into freed slot
            }
            __syncthreads();
        }
    }

    // ---- epilogue: C/D layout col=lane&15, row=(lane>>4)*4+r ----
    const int orow  = m0 + wv * 16 + kg * 4;
    const int fbase = g * FDIM;
#pragma unroll
    for (int t = 0; t < NTILE; ++t) {
        const int fc = t * 16 + r16;
        if (fc < FDIM) {
            const float bv = Bv[fbase + fc];
#pragma unroll
            for (int r = 0; r < 4; ++r) {
                Out[(size_t)(orow + r) * NCLS + fbase + fc] = acc[t][r] + bv;
            }
        }
    }
}

extern "C" void kernel_launch(void* const* d_in, const int* in_sizes, int n_in,
                              void* d_out, int out_size, void* d_ws, size_t ws_size,
                              hipStream_t stream) {
    const float* H  = (const float*)d_in[0];   // (512, 100, 768) f32
    const float* W  = (const float*)d_in[1];   // (100, 768, 100) f32
    const float* Bv = (const float*)d_in[2];   // (10000,) f32
    float* Out = (float*)d_out;                // (512, 10000) f32
    gfcp_mfma<<<dim3(800), dim3(256), 0, stream>>>(H, W, Bv, Out);
}